// Round 5
// baseline (415.114 us; speedup 1.0000x reference)
//
#include <hip/hip_runtime.h>
#include <hip/hip_fp16.h>

// HungarianMatcher cost C[16,1500,2400] = 5*L1 + focal_class + 2*(-GIoU)
// v5 = v4 with the occupancy lever pulled. v1/v2/v4 all stall ~55% with
// neither VALU (~23us) nor stores (~37us) saturated at ~16 waves/CU ->
// latency-bound. Changes:
//  - __launch_bounds__(256, 8): target 8 waves/SIMD (32/CU, was ~4-5/SIMD)
//  - per-thread state slimmed to fit ~64 VGPR: only cxcywh (16) + LDS
//    byte-addrs (4) persist; box corners REMATERIALIZED per element
//    (4 fma/elem, +3us chip-wide VALU - cheap vs halving latency stalls)
//  - everything else = v4: 8 queries/block x all 2400 targets (3 tiles),
//    fp16 [class][q] table built once, ds_read_b64 = 4 queries' class cost,
//    nontemporal float4 stores
// Floors: stores 230MB ~37us, VALU ~26us.

namespace {
constexpr int kBS = 16, kQ = 1500, kK = 256, kNT = 150;
constexpr int kT   = kBS * kNT;   // 2400
constexpr int kN   = kBS * kQ;    // 24000
constexpr int kQB  = 8;           // queries per block
constexpr float kAlpha = 0.25f;
constexpr float kEps   = 1e-8f;
typedef float floatx4 __attribute__((ext_vector_type(4)));
}

__global__ __launch_bounds__(256, 8)
void matcher_cost_kernel(const float* __restrict__ logits,   // [N,256]
                         const float* __restrict__ pboxes,   // [N,4] cxcywh
                         const float* __restrict__ tboxes,   // [T,4] cxcywh
                         const int*   __restrict__ tids,     // [T]
                         float* __restrict__ out)            // [N,T]
{
    // [class][q/2] half2, row stride 6 half2 = 24B (cols 4,5 pad). 6 KB.
    __shared__ __align__(16) __half2 s_fcl[kK][6];

    const int tid = threadIdx.x;
    const int n0  = blockIdx.x * kQB;

    // ---- focal class-cost table (cc + 2.0 folded), thread = class ----
    {
        const float* lrow = logits + (size_t)n0 * kK + tid;
#pragma unroll
        for (int qp = 0; qp < kQB / 2; ++qp) {
            float c[2];
#pragma unroll
            for (int j = 0; j < 2; ++j) {
                const float x   = lrow[(2 * qp + j) * kK];
                const float p   = __builtin_amdgcn_rcpf(1.0f + __expf(-x));
                const float omp = 1.0f - p;
                c[j] = -kAlpha * omp * omp * __logf(p + kEps)
                     + (1.0f - kAlpha) * p * p * __logf(omp + kEps) + 2.0f;
            }
            s_fcl[tid][qp] = __floats2half2_rn(c[0], c[1]);
        }
    }
    __syncthreads();   // the only barrier; LDS read-only below

    const float4* __restrict__ tb4   = reinterpret_cast<const float4*>(tboxes);
    const char*   __restrict__ fbase = reinterpret_cast<const char*>(s_fcl);

    auto tilework = [&](int tbase) {   // 4 consecutive targets [tbase, tbase+4)
        const int4 ci = *reinterpret_cast<const int4*>(tids + tbase);
        const int laddr[4] = {ci.x * 24, ci.y * 24, ci.z * 24, ci.w * 24};
        float4 tb[4];   // cxcywh only - corners rematerialized per element
#pragma unroll
        for (int e = 0; e < 4; ++e) tb[e] = tb4[tbase + e];
        float* __restrict__ ob = out + (size_t)n0 * kT + tbase;

#pragma unroll
        for (int qg = 0; qg < kQB / 4; ++qg) {
            uint2 ccr[4];   // one b64 per target = class cost for 4 queries
#pragma unroll
            for (int e = 0; e < 4; ++e)
                ccr[e] = *reinterpret_cast<const uint2*>(
                             fbase + laddr[e] + qg * 8);

#pragma unroll
            for (int qi = 0; qi < 4; ++qi) {
                const int q = qg * 4 + qi;
                const float4 pb = *reinterpret_cast<const float4*>(
                                      pboxes + (size_t)(n0 + q) * 4);
                const float pcx = pb.x, pcy = pb.y, pw = pb.z, ph = pb.w;
                const float px1 = fmaf(-0.5f, pw, pcx), px2 = fmaf(0.5f, pw, pcx);
                const float py1 = fmaf(-0.5f, ph, pcy), py2 = fmaf(0.5f, ph, pcy);
                const float parea = pw * ph;

                floatx4 res;
#pragma unroll
                for (int e = 0; e < 4; ++e) {
                    const unsigned u  = (qi < 2) ? ccr[e].x : ccr[e].y;  // qi const
                    const __half2 h2  = *reinterpret_cast<const __half2*>(&u);
                    const float   cc  = (qi & 1) ? __high2float(h2) : __low2float(h2);
                    const float bcx = tb[e].x, bcy = tb[e].y;
                    const float bw  = tb[e].z, bh  = tb[e].w;
                    // L1 cost (cxcywh space)
                    const float cb = fabsf(pcx - bcx) + fabsf(pcy - bcy)
                                   + fabsf(pw - bw)  + fabsf(ph - bh);
                    // corners rematerialized (cheap fma; keeps VGPR low)
                    const float bx1 = fmaf(-0.5f, bw, bcx), bx2 = fmaf(0.5f, bw, bcx);
                    const float by1 = fmaf(-0.5f, bh, bcy), by2 = fmaf(0.5f, bh, bcy);
                    // overlap; enclose via identity ew = pw+bw-ow
                    const float ow = fminf(px2, bx2) - fmaxf(px1, bx1);
                    const float oh = fminf(py2, by2) - fmaxf(py1, by1);
                    const float iw = fmaxf(ow, 0.0f), ih = fmaxf(oh, 0.0f);
                    const float ew = (pw + bw) - ow, eh = (ph + bh) - oh;
                    const float inter = iw * ih;
                    const float uni   = fmaf(bw, bh, parea) - inter;
                    const float ear   = ew * eh;
                    // out = 5cb + (cc+2) - 2*(inter*ear + uni*uni)/(uni*ear)
                    const float rr   = __builtin_amdgcn_rcpf(uni * ear);
                    const float frac = fmaf(uni, uni, inter * ear) * rr;
                    res[e] = fmaf(-2.0f, frac, fmaf(5.0f, cb, cc));
                }
                __builtin_nontemporal_store(
                    res, reinterpret_cast<floatx4*>(ob + (size_t)q * kT));
            }
        }
    };

    // tiles: [0,1024) [1024,2048) [2048,2400)
    const int o4 = tid << 2;
    tilework(o4);
    tilework(1024 + o4);
    if (o4 < 352) tilework(2048 + o4);   // most waves retire early
}

extern "C" void kernel_launch(void* const* d_in, const int* in_sizes, int n_in,
                              void* d_out, int out_size, void* d_ws, size_t ws_size,
                              hipStream_t stream) {
    const float* logits = (const float*)d_in[0];   // [16,1500,256]
    const float* pboxes = (const float*)d_in[1];   // [16,1500,4]
    const float* tboxes = (const float*)d_in[2];   // [2400,4]
    const int*   tids   = (const int*)d_in[3];     // [2400]
    float* out = (float*)d_out;                    // [16,1500,2400] fp32

    dim3 grid(kN / kQB);   // 3000 blocks
    dim3 block(256);
    hipLaunchKernelGGL(matcher_cost_kernel, grid, block, 0, stream,
                       logits, pboxes, tboxes, tids, out);
}

// Round 6
// 264.962 us; speedup vs baseline: 1.5667x; 1.5667x over previous
//
#include <hip/hip_runtime.h>
#include <hip/hip_fp16.h>

// HungarianMatcher cost C[16,1500,2400] = 5*L1 + focal_class + 2*(-GIoU)
// v6 = v5 body with the occupancy bound backed off the spill cliff.
// v5 post-mortem: __launch_bounds__(256,8) -> 32 VGPR via SCRATCH SPILLS
// (WRITE 514MB vs 230MB output, FETCH 214MB, kernel 221us). The allocator
// spills, not rematerializes, past the cliff.
//  - __launch_bounds__(256, 6): VGPR cap 84 (slim body needs ~60-70), no
//    spill, 6 waves/SIMD = 24 waves/CU (v4 was 16 at bound 4)
//  - per-thread state: cxcywh only (16 regs) + LDS byte-addrs; corners
//    rematerialized per element (fma is cheaper than latency stalls)
//  - 8 queries/block x all 2400 targets (3 tiles), fp16 [class][q] table
//    built once, ds_read_b64 = 4 queries' class cost, nontemporal stores
// Floors: stores 230MB ~37us, VALU ~26us.

namespace {
constexpr int kBS = 16, kQ = 1500, kK = 256, kNT = 150;
constexpr int kT   = kBS * kNT;   // 2400
constexpr int kN   = kBS * kQ;    // 24000
constexpr int kQB  = 8;           // queries per block
constexpr float kAlpha = 0.25f;
constexpr float kEps   = 1e-8f;
typedef float floatx4 __attribute__((ext_vector_type(4)));
}

__global__ __launch_bounds__(256, 6)
void matcher_cost_kernel(const float* __restrict__ logits,   // [N,256]
                         const float* __restrict__ pboxes,   // [N,4] cxcywh
                         const float* __restrict__ tboxes,   // [T,4] cxcywh
                         const int*   __restrict__ tids,     // [T]
                         float* __restrict__ out)            // [N,T]
{
    // [class][q/2] half2, row stride 6 half2 = 24B (cols 4,5 pad). 6 KB.
    __shared__ __align__(16) __half2 s_fcl[kK][6];

    const int tid = threadIdx.x;
    const int n0  = blockIdx.x * kQB;

    // ---- focal class-cost table (cc + 2.0 folded), thread = class ----
    {
        const float* lrow = logits + (size_t)n0 * kK + tid;
#pragma unroll
        for (int qp = 0; qp < kQB / 2; ++qp) {
            float c[2];
#pragma unroll
            for (int j = 0; j < 2; ++j) {
                const float x   = lrow[(2 * qp + j) * kK];
                const float p   = __builtin_amdgcn_rcpf(1.0f + __expf(-x));
                const float omp = 1.0f - p;
                c[j] = -kAlpha * omp * omp * __logf(p + kEps)
                     + (1.0f - kAlpha) * p * p * __logf(omp + kEps) + 2.0f;
            }
            s_fcl[tid][qp] = __floats2half2_rn(c[0], c[1]);
        }
    }
    __syncthreads();   // the only barrier; LDS read-only below

    const float4* __restrict__ tb4   = reinterpret_cast<const float4*>(tboxes);
    const char*   __restrict__ fbase = reinterpret_cast<const char*>(s_fcl);

    auto tilework = [&](int tbase) {   // 4 consecutive targets [tbase, tbase+4)
        const int4 ci = *reinterpret_cast<const int4*>(tids + tbase);
        const int laddr[4] = {ci.x * 24, ci.y * 24, ci.z * 24, ci.w * 24};
        float4 tb[4];   // cxcywh only - corners rematerialized per element
#pragma unroll
        for (int e = 0; e < 4; ++e) tb[e] = tb4[tbase + e];
        float* __restrict__ ob = out + (size_t)n0 * kT + tbase;

#pragma unroll
        for (int qg = 0; qg < kQB / 4; ++qg) {
            uint2 ccr[4];   // one b64 per target = class cost for 4 queries
#pragma unroll
            for (int e = 0; e < 4; ++e)
                ccr[e] = *reinterpret_cast<const uint2*>(
                             fbase + laddr[e] + qg * 8);

#pragma unroll
            for (int qi = 0; qi < 4; ++qi) {
                const int q = qg * 4 + qi;
                const float4 pb = *reinterpret_cast<const float4*>(
                                      pboxes + (size_t)(n0 + q) * 4);
                const float pcx = pb.x, pcy = pb.y, pw = pb.z, ph = pb.w;
                const float px1 = fmaf(-0.5f, pw, pcx), px2 = fmaf(0.5f, pw, pcx);
                const float py1 = fmaf(-0.5f, ph, pcy), py2 = fmaf(0.5f, ph, pcy);
                const float parea = pw * ph;

                floatx4 res;
#pragma unroll
                for (int e = 0; e < 4; ++e) {
                    const unsigned u  = (qi < 2) ? ccr[e].x : ccr[e].y;  // qi const
                    const __half2 h2  = *reinterpret_cast<const __half2*>(&u);
                    const float   cc  = (qi & 1) ? __high2float(h2) : __low2float(h2);
                    const float bcx = tb[e].x, bcy = tb[e].y;
                    const float bw  = tb[e].z, bh  = tb[e].w;
                    // L1 cost (cxcywh space)
                    const float cb = fabsf(pcx - bcx) + fabsf(pcy - bcy)
                                   + fabsf(pw - bw)  + fabsf(ph - bh);
                    // corners rematerialized (cheap fma; keeps VGPR low)
                    const float bx1 = fmaf(-0.5f, bw, bcx), bx2 = fmaf(0.5f, bw, bcx);
                    const float by1 = fmaf(-0.5f, bh, bcy), by2 = fmaf(0.5f, bh, bcy);
                    // overlap; enclose via identity ew = pw+bw-ow
                    const float ow = fminf(px2, bx2) - fmaxf(px1, bx1);
                    const float oh = fminf(py2, by2) - fmaxf(py1, by1);
                    const float iw = fmaxf(ow, 0.0f), ih = fmaxf(oh, 0.0f);
                    const float ew = (pw + bw) - ow, eh = (ph + bh) - oh;
                    const float inter = iw * ih;
                    const float uni   = fmaf(bw, bh, parea) - inter;
                    const float ear   = ew * eh;
                    // out = 5cb + (cc+2) - 2*(inter*ear + uni*uni)/(uni*ear)
                    const float rr   = __builtin_amdgcn_rcpf(uni * ear);
                    const float frac = fmaf(uni, uni, inter * ear) * rr;
                    res[e] = fmaf(-2.0f, frac, fmaf(5.0f, cb, cc));
                }
                __builtin_nontemporal_store(
                    res, reinterpret_cast<floatx4*>(ob + (size_t)q * kT));
            }
        }
    };

    // tiles: [0,1024) [1024,2048) [2048,2400)
    const int o4 = tid << 2;
    tilework(o4);
    tilework(1024 + o4);
    if (o4 < 352) tilework(2048 + o4);   // most waves retire early
}

extern "C" void kernel_launch(void* const* d_in, const int* in_sizes, int n_in,
                              void* d_out, int out_size, void* d_ws, size_t ws_size,
                              hipStream_t stream) {
    const float* logits = (const float*)d_in[0];   // [16,1500,256]
    const float* pboxes = (const float*)d_in[1];   // [16,1500,4]
    const float* tboxes = (const float*)d_in[2];   // [2400,4]
    const int*   tids   = (const int*)d_in[3];     // [2400]
    float* out = (float*)d_out;                    // [16,1500,2400] fp32

    dim3 grid(kN / kQB);   // 3000 blocks
    dim3 block(256);
    hipLaunchKernelGGL(matcher_cost_kernel, grid, block, 0, stream,
                       logits, pboxes, tboxes, tids, out);
}